// Round 2
// 1820.214 us; speedup vs baseline: 1.2491x; 1.2491x over previous
//
#include <hip/hip_runtime.h>

#define N_TOT 100000
#define IN_F  500
#define H_F   256
#define M_ROWS 50000
#define K_CL  40
#define OUT2  1024
#define BN_EPS 1e-5f

typedef __attribute__((ext_vector_type(8))) short bf16x8;
typedef __attribute__((ext_vector_type(4))) float f32x4;

// fp32 -> bf16 round-to-nearest-even
__device__ __forceinline__ unsigned short f2bf(float f) {
    unsigned u = __float_as_uint(f);
    u += 0x7fffu + ((u >> 16) & 1u);
    return (unsigned short)(u >> 16);
}

// ---------------------------------------------------------------------------
// Generic tiled fp32 GEMM (kept for L1/L2/P/Q):
// C[r, c] = sum_k A[ar(r), k] * B[c*ldb + boff + k] (+ bias[c]) (+ addvec)
// ---------------------------------------------------------------------------
template <bool HAS_IDX, bool HAS_ADD>
__global__ __launch_bounds__(256) void gemm_kernel(
    const float* __restrict__ A, int lda,
    const float* __restrict__ B, int ldb, int boff,
    const float* __restrict__ bias,
    const float* __restrict__ addvec, const int* __restrict__ addidx,
    const int* __restrict__ rowidx,
    float* __restrict__ C, int ldc,
    int Mrows, int Ncols, int Kdim)
{
    __shared__ float As[16][68];
    __shared__ float Bs[16][68];
    const int tid = threadIdx.x;
    const int tx = tid & 15;   // col group (4 cols)
    const int ty = tid >> 4;   // row group (4 rows)
    const int rowBase = blockIdx.x * 64;
    const int colBase = blockIdx.y * 64;

    const int l_r = tid >> 2;         // 0..63 tile row
    const int l_k = (tid & 3) << 2;   // 0,4,8,12

    const int growA = rowBase + l_r;
    const bool aok = growA < Mrows;
    long abase = 0;
    if (aok) {
        const int ar = HAS_IDX ? rowidx[growA] : growA;
        abase = (long)ar * lda;
    }
    const long bbase = (long)(colBase + l_r) * ldb + boff;

    float acc[4][4] = {};

    for (int k0 = 0; k0 < Kdim; k0 += 16) {
        const int kk = k0 + l_k;
        float4 av = make_float4(0.f, 0.f, 0.f, 0.f);
        if (aok) {
            const float* ap = A + abase + kk;
            if (kk + 3 < Kdim) {
                av = *reinterpret_cast<const float4*>(ap);
            } else {
                if (kk     < Kdim) av.x = ap[0];
                if (kk + 1 < Kdim) av.y = ap[1];
                if (kk + 2 < Kdim) av.z = ap[2];
                if (kk + 3 < Kdim) av.w = ap[3];
            }
        }
        As[l_k + 0][l_r] = av.x;
        As[l_k + 1][l_r] = av.y;
        As[l_k + 2][l_r] = av.z;
        As[l_k + 3][l_r] = av.w;

        float4 bv = make_float4(0.f, 0.f, 0.f, 0.f);
        {
            const float* bp = B + bbase + kk;
            if (kk + 3 < Kdim) {
                bv = *reinterpret_cast<const float4*>(bp);
            } else {
                if (kk     < Kdim) bv.x = bp[0];
                if (kk + 1 < Kdim) bv.y = bp[1];
                if (kk + 2 < Kdim) bv.z = bp[2];
                if (kk + 3 < Kdim) bv.w = bp[3];
            }
        }
        Bs[l_k + 0][l_r] = bv.x;
        Bs[l_k + 1][l_r] = bv.y;
        Bs[l_k + 2][l_r] = bv.z;
        Bs[l_k + 3][l_r] = bv.w;

        __syncthreads();

        #pragma unroll
        for (int k = 0; k < 16; k++) {
            const float4 ra = *reinterpret_cast<const float4*>(&As[k][ty << 2]);
            const float4 rb = *reinterpret_cast<const float4*>(&Bs[k][tx << 2]);
            const float a_[4] = {ra.x, ra.y, ra.z, ra.w};
            const float b_[4] = {rb.x, rb.y, rb.z, rb.w};
            #pragma unroll
            for (int i = 0; i < 4; i++)
                #pragma unroll
                for (int j = 0; j < 4; j++)
                    acc[i][j] = fmaf(a_[i], b_[j], acc[i][j]);
        }
        __syncthreads();
    }

    const int c0 = colBase + (tx << 2);
    float4 badd = make_float4(0.f, 0.f, 0.f, 0.f);
    if (bias) badd = *reinterpret_cast<const float4*>(&bias[c0]);
    #pragma unroll
    for (int i = 0; i < 4; i++) {
        const int r = rowBase + (ty << 2) + i;
        if (r < Mrows) {
            float4 v;
            v.x = acc[i][0] + badd.x;
            v.y = acc[i][1] + badd.y;
            v.z = acc[i][2] + badd.z;
            v.w = acc[i][3] + badd.w;
            if (HAS_ADD) {
                const int lab = addidx[r];
                const float4 p =
                    *reinterpret_cast<const float4*>(&addvec[(long)lab * OUT2 + c0]);
                v.x += p.x; v.y += p.y; v.z += p.z; v.w += p.w;
            }
            *reinterpret_cast<float4*>(&C[(long)r * ldc + c0]) = v;
        }
    }
}

// ---------------------------------------------------------------------------
// Fused bf16-MFMA final GEMM. Replaces BOTH fp32 final GEMMs.
// half = blockIdx.y>>3:  0 -> xc @ WfcA.T + P[label] + bfc  -> out[0..M)
//                        1 -> xc @ WfcB.T + Q[label] + bfc  -> out[M..2M)
// Block: 128(M) x 128(N) tile, 4 waves at 64x64 each, mfma_f32_16x16x32_bf16.
// LDS rows padded +8 ushort (stride 144B) => ~2-way bank aliasing (free).
// Fragment layout: A/B lane l elem j = [l&15][(l>>4)*8+j] (16B contiguous);
// D: col=lane&15, row=(lane>>4)*4+reg (m89-verified).
// ---------------------------------------------------------------------------
__global__ __launch_bounds__(256) void final_gemm_bf16(
    const unsigned short* __restrict__ Ab,   // h2 bf16 [N_TOT][H_F]
    const unsigned short* __restrict__ Wb,   // Wfc bf16 [OUT2][2*H_F]
    const float* __restrict__ bias,          // bfc [OUT2]
    const float* __restrict__ P,             // [K_CL][OUT2]  (cf @ WfcB.T)
    const float* __restrict__ Q,             // [K_CL][OUT2]  (cf @ WfcA.T)
    const int* __restrict__ labels,
    const int* __restrict__ rowidx,
    float* __restrict__ out)                 // [2*M_ROWS][OUT2]
{
    __shared__ __align__(16) unsigned short As[128][72];
    __shared__ __align__(16) unsigned short Bs[128][72];

    const int tid  = threadIdx.x;
    const int wave = tid >> 6;
    const int lane = tid & 63;
    const int wr = (wave >> 1) * 64;   // wave row offset in tile
    const int wc = (wave & 1) * 64;    // wave col offset in tile
    const int lr = lane & 15;
    const int lk = (lane >> 4) << 3;   // 0,8,16,24

    const int mbase = blockIdx.x * 128;
    const int half  = blockIdx.y >> 3;
    const int nbase = (blockIdx.y & 7) * 128;
    const int boff  = half ? H_F : 0;  // Wfc column offset (elements)

    // staging: 8 threads/row, 16B (8 bf16) each; rows s_row, +32, +64, +96
    const int s_row = tid >> 3;          // 0..31
    const int s_k   = (tid & 7) << 3;    // 0..56

    long arow[4];
    #pragma unroll
    for (int i = 0; i < 4; i++) {
        const int gm = mbase + s_row + 32 * i;
        const int r = (gm < M_ROWS) ? rowidx[gm] : 0;
        arow[i] = (long)r * H_F + s_k;
    }
    long brow[4];
    #pragma unroll
    for (int i = 0; i < 4; i++)
        brow[i] = (long)(nbase + s_row + 32 * i) * (2 * H_F) + boff + s_k;

    f32x4 acc[4][4];
    #pragma unroll
    for (int f = 0; f < 4; f++)
        #pragma unroll
        for (int g = 0; g < 4; g++)
            acc[f][g] = f32x4{0.f, 0.f, 0.f, 0.f};

    for (int k0 = 0; k0 < H_F; k0 += 64) {
        #pragma unroll
        for (int i = 0; i < 4; i++) {
            const uint4 va = *reinterpret_cast<const uint4*>(Ab + arow[i] + k0);
            *reinterpret_cast<uint4*>(&As[s_row + 32 * i][s_k]) = va;
        }
        #pragma unroll
        for (int i = 0; i < 4; i++) {
            const uint4 vb = *reinterpret_cast<const uint4*>(Wb + brow[i] + k0);
            *reinterpret_cast<uint4*>(&Bs[s_row + 32 * i][s_k]) = vb;
        }
        __syncthreads();

        #pragma unroll
        for (int kk = 0; kk < 64; kk += 32) {
            bf16x8 af[4], bfr[4];
            #pragma unroll
            for (int f = 0; f < 4; f++)
                af[f] = *reinterpret_cast<const bf16x8*>(&As[wr + f * 16 + lr][kk + lk]);
            #pragma unroll
            for (int g = 0; g < 4; g++)
                bfr[g] = *reinterpret_cast<const bf16x8*>(&Bs[wc + g * 16 + lr][kk + lk]);
            #pragma unroll
            for (int f = 0; f < 4; f++)
                #pragma unroll
                for (int g = 0; g < 4; g++)
                    acc[f][g] = __builtin_amdgcn_mfma_f32_16x16x32_bf16(
                        af[f], bfr[g], acc[f][g], 0, 0, 0);
        }
        __syncthreads();
    }

    const float* __restrict__ addv = half ? Q : P;
    float* __restrict__ outp = out + (half ? (long)M_ROWS * OUT2 : 0);
    const int rbase = (lane >> 4) << 2;
    #pragma unroll
    for (int f = 0; f < 4; f++) {
        #pragma unroll
        for (int r = 0; r < 4; r++) {
            const int m = mbase + wr + f * 16 + rbase + r;
            if (m < M_ROWS) {
                const long lab = labels[m];
                const float* pv = addv + lab * OUT2;
                float* orow = outp + (long)m * OUT2;
                #pragma unroll
                for (int g = 0; g < 4; g++) {
                    const int c = nbase + wc + g * 16 + lr;
                    orow[c] = acc[f][g][r] + bias[c] + pv[c];
                }
            }
        }
    }
}

// Column sums + sumsq over h[rows, 256]. sums[0..255]=sum, sums[256..511]=sumsq.
__global__ __launch_bounds__(256) void bn_stats(
    const float* __restrict__ h, int rows, float* __restrict__ sums)
{
    const int col = threadIdx.x;
    const int per = (rows + gridDim.x - 1) / gridDim.x;
    const int r0 = blockIdx.x * per;
    const int r1 = min(rows, r0 + per);
    float s = 0.f, ss = 0.f;
    for (int r = r0; r < r1; r++) {
        const float v = h[(long)r * H_F + col];
        s += v;
        ss = fmaf(v, v, ss);
    }
    atomicAdd(&sums[col], s);
    atomicAdd(&sums[col + H_F], ss);
}

__global__ __launch_bounds__(256) void bn_finalize(
    const float* __restrict__ sums, const float* __restrict__ g,
    const float* __restrict__ beta, float* __restrict__ ss_out)
{
    const int j = threadIdx.x;
    const float invN = 1.0f / (float)N_TOT;
    const float mean = sums[j] * invN;
    const float var  = sums[j + H_F] * invN - mean * mean;
    const float rs = rsqrtf(var + BN_EPS);
    const float sc = rs * g[j];
    ss_out[j] = sc;
    ss_out[j + H_F] = beta[j] - mean * sc;
}

// In-place y = relu(x*scale[col] + shift[col]); optionally also write bf16 copy.
__global__ __launch_bounds__(256) void bn_relu(
    float* __restrict__ h, const float* __restrict__ ss, int total4,
    unsigned short* __restrict__ hb)
{
    const int i = blockIdx.x * blockDim.x + threadIdx.x;
    if (i < total4) {
        float4 v = reinterpret_cast<float4*>(h)[i];
        const int c = (i << 2) & (H_F - 1);
        v.x = fmaxf(0.f, fmaf(v.x, ss[c + 0], ss[c + 256]));
        v.y = fmaxf(0.f, fmaf(v.y, ss[c + 1], ss[c + 257]));
        v.z = fmaxf(0.f, fmaf(v.z, ss[c + 2], ss[c + 258]));
        v.w = fmaxf(0.f, fmaf(v.w, ss[c + 3], ss[c + 259]));
        reinterpret_cast<float4*>(h)[i] = v;
        if (hb) {
            ushort4 b;
            b.x = f2bf(v.x); b.y = f2bf(v.y); b.z = f2bf(v.z); b.w = f2bf(v.w);
            reinterpret_cast<ushort4*>(hb)[i] = b;
        }
    }
}

// fp32 -> bf16 bulk cast (float4 -> ushort4 per thread)
__global__ __launch_bounds__(256) void cast_to_bf16(
    const float* __restrict__ src, unsigned short* __restrict__ dst, int n4)
{
    const int i = blockIdx.x * blockDim.x + threadIdx.x;
    if (i < n4) {
        const float4 v = reinterpret_cast<const float4*>(src)[i];
        ushort4 b;
        b.x = f2bf(v.x); b.y = f2bf(v.y); b.z = f2bf(v.z); b.w = f2bf(v.w);
        reinterpret_cast<ushort4*>(dst)[i] = b;
    }
}

// labels[m] = argmax(cluster_id[m,:])
__global__ __launch_bounds__(256) void labels_kernel(
    const float* __restrict__ cid, int* __restrict__ labels, int* __restrict__ counts)
{
    const int m = blockIdx.x * blockDim.x + threadIdx.x;
    if (m < M_ROWS) {
        const float* row = cid + (long)m * K_CL;
        int best = 0;
        float bv = row[0];
        for (int k = 1; k < K_CL; k++) {
            const float v = row[k];
            if (v > bv) { bv = v; best = k; }
        }
        labels[m] = best;
        atomicAdd(&counts[best], 1);
    }
}

// Per-block LDS [K,H] accumulator; thread j owns column j.
__global__ __launch_bounds__(256) void seg_sum(
    const float* __restrict__ h2, const int* __restrict__ cidx,
    const int* __restrict__ labels, float* __restrict__ csum)
{
    __shared__ float ls[K_CL * H_F];
    for (int i = threadIdx.x; i < K_CL * H_F; i += blockDim.x) ls[i] = 0.f;
    __syncthreads();
    const int per = (M_ROWS + gridDim.x - 1) / gridDim.x;
    const int m0 = blockIdx.x * per;
    const int m1 = min(M_ROWS, m0 + per);
    const int j = threadIdx.x;
    for (int m = m0; m < m1; m++) {
        const int lab = labels[m];
        const int row = cidx[m];
        ls[lab * H_F + j] += h2[(long)row * H_F + j];
    }
    __syncthreads();
    for (int i = threadIdx.x; i < K_CL * H_F; i += blockDim.x) {
        const float v = ls[i];
        if (v != 0.f) atomicAdd(&csum[i], v);
    }
}

__global__ __launch_bounds__(256) void cf_kernel(
    const float* __restrict__ csum, const int* __restrict__ counts,
    float* __restrict__ cf)
{
    const int i = blockIdx.x * blockDim.x + threadIdx.x;
    if (i < K_CL * H_F) {
        const int k = i >> 8;
        cf[i] = csum[i] / (float)counts[k];
    }
}

extern "C" void kernel_launch(void* const* d_in, const int* in_sizes, int n_in,
                              void* d_out, int out_size, void* d_ws, size_t ws_size,
                              hipStream_t stream)
{
    const float* x    = (const float*)d_in[0];
    const float* cid  = (const float*)d_in[1];
    const int*   cidx = (const int*)  d_in[2];
    const float* W1   = (const float*)d_in[3];
    const float* b1   = (const float*)d_in[4];
    const float* g1   = (const float*)d_in[5];
    const float* be1  = (const float*)d_in[6];
    const float* W2   = (const float*)d_in[7];
    const float* b2   = (const float*)d_in[8];
    const float* g2   = (const float*)d_in[9];
    const float* be2  = (const float*)d_in[10];
    const float* Wfc  = (const float*)d_in[11];
    const float* bfc  = (const float*)d_in[12];
    float* out = (float*)d_out;

    char* ws = (char*)d_ws;
    size_t off = 0;
    auto alloc = [&](size_t bytes) -> void* {
        void* p = ws + off;
        off += (bytes + 255) & ~(size_t)255;
        return p;
    };
    float* h1    = (float*)alloc((size_t)N_TOT * H_F * 4);
    float* h2    = (float*)alloc((size_t)N_TOT * H_F * 4);
    float* sums1 = (float*)alloc(2 * H_F * 4);
    float* ss1   = (float*)alloc(2 * H_F * 4);
    float* sums2 = (float*)alloc(2 * H_F * 4);
    float* ss2   = (float*)alloc(2 * H_F * 4);
    int*   counts= (int*)  alloc(K_CL * 4);
    int*   labels= (int*)  alloc(M_ROWS * 4);
    float* csum  = (float*)alloc(K_CL * H_F * 4);
    float* cf    = (float*)alloc(K_CL * H_F * 4);
    float* P     = (float*)alloc((size_t)K_CL * OUT2 * 4);
    float* Q     = (float*)alloc((size_t)K_CL * OUT2 * 4);
    (void)ws_size; (void)in_sizes; (void)n_in; (void)out_size;

    // bf16 buffers alias h1 (h1 is dead after the L2 GEMM reads it):
    //   h2b  = bf16(h2)  [N_TOT*H_F*2 = 51.2 MB]
    //   wfcb = bf16(Wfc) [OUT2*2*H_F*2 = 1 MB], placed right after h2b
    unsigned short* h2b  = (unsigned short*)h1;
    unsigned short* wfcb = h2b + (size_t)N_TOT * H_F;

    // Zero the accumulator span (sums1 .. csum inclusive; ws is poisoned 0xAA).
    {
        char* z0 = (char*)sums1;
        char* z1 = (char*)csum + ((K_CL * H_F * 4 + 255) & ~255);
        hipMemsetAsync(z0, 0, (size_t)(z1 - z0), stream);
    }

    const dim3 blk(256);

    // labels + counts (independent of the GEMM chain)
    labels_kernel<<<dim3((M_ROWS + 255) / 256), blk, 0, stream>>>(cid, labels, counts);

    // layer 1: h1 = relu(bn(x @ W1.T + b1))
    gemm_kernel<false, false><<<dim3((N_TOT + 63) / 64, H_F / 64), blk, 0, stream>>>(
        x, IN_F, W1, IN_F, 0, b1, nullptr, nullptr, nullptr, h1, H_F, N_TOT, H_F, IN_F);
    bn_stats<<<dim3(256), blk, 0, stream>>>(h1, N_TOT, sums1);
    bn_finalize<<<dim3(1), blk, 0, stream>>>(sums1, g1, be1, ss1);
    bn_relu<<<dim3((N_TOT * H_F / 4 + 255) / 256), blk, 0, stream>>>(
        h1, ss1, N_TOT * H_F / 4, nullptr);

    // layer 2: h2 = relu(bn(h1 @ W2.T + b2))  (last reader of h1)
    gemm_kernel<false, false><<<dim3((N_TOT + 63) / 64, H_F / 64), blk, 0, stream>>>(
        h1, H_F, W2, H_F, 0, b2, nullptr, nullptr, nullptr, h2, H_F, N_TOT, H_F, H_F);

    // h1 is now dead: safe to overwrite its buffer with bf16 data.
    cast_to_bf16<<<dim3((OUT2 * 2 * H_F / 4 + 255) / 256), blk, 0, stream>>>(
        Wfc, wfcb, OUT2 * 2 * H_F / 4);

    bn_stats<<<dim3(256), blk, 0, stream>>>(h2, N_TOT, sums2);
    bn_finalize<<<dim3(1), blk, 0, stream>>>(sums2, g2, be2, ss2);
    bn_relu<<<dim3((N_TOT * H_F / 4 + 255) / 256), blk, 0, stream>>>(
        h2, ss2, N_TOT * H_F / 4, h2b);

    // cluster mean features cf[K,H] (fp32 path, unchanged)
    seg_sum<<<dim3(100), blk, 0, stream>>>(h2, cidx, labels, csum);
    cf_kernel<<<dim3((K_CL * H_F + 255) / 256), blk, 0, stream>>>(csum, counts, cf);

    // P = cf @ WfcB.T ; Q = cf @ WfcA.T   (tiny, fp32, unchanged)
    gemm_kernel<false, false><<<dim3(1, OUT2 / 64), blk, 0, stream>>>(
        cf, H_F, Wfc, 2 * H_F, H_F, nullptr, nullptr, nullptr, nullptr, P, OUT2, K_CL, OUT2, H_F);
    gemm_kernel<false, false><<<dim3(1, OUT2 / 64), blk, 0, stream>>>(
        cf, H_F, Wfc, 2 * H_F, 0, nullptr, nullptr, nullptr, nullptr, Q, OUT2, K_CL, OUT2, H_F);

    // Fused bf16-MFMA final GEMM:
    //   y<8 :  out[m]     = xc@WfcA.T + P[label[m]] + bfc
    //   y>=8:  out[M+m]   = xc@WfcB.T + Q[label[m]] + bfc
    final_gemm_bf16<<<dim3((M_ROWS + 127) / 128, 16), blk, 0, stream>>>(
        h2b, wfcb, bfc, P, Q, labels, cidx, out);
}

// Round 3
// 1469.870 us; speedup vs baseline: 1.5468x; 1.2384x over previous
//
#include <hip/hip_runtime.h>

#define N_TOT 100000
#define IN_F  500
#define H_F   256
#define M_ROWS 50000
#define K_CL  40
#define OUT2  1024
#define BN_EPS 1e-5f

typedef __attribute__((ext_vector_type(8))) short bf16x8;
typedef __attribute__((ext_vector_type(8))) _Float16 f16x8;
typedef __attribute__((ext_vector_type(4))) float f32x4;

// fp32 -> bf16 round-to-nearest-even
__device__ __forceinline__ unsigned short f2bf(float f) {
    unsigned u = __float_as_uint(f);
    u += 0x7fffu + ((u >> 16) & 1u);
    return (unsigned short)(u >> 16);
}

// ---------------------------------------------------------------------------
// Generic tiled fp32 GEMM (kept for tiny P/Q GEMMs only):
// C[r, c] = sum_k A[r, k] * B[c*ldb + boff + k] (+ bias[c])
// ---------------------------------------------------------------------------
template <bool HAS_IDX, bool HAS_ADD>
__global__ __launch_bounds__(256) void gemm_kernel(
    const float* __restrict__ A, int lda,
    const float* __restrict__ B, int ldb, int boff,
    const float* __restrict__ bias,
    const float* __restrict__ addvec, const int* __restrict__ addidx,
    const int* __restrict__ rowidx,
    float* __restrict__ C, int ldc,
    int Mrows, int Ncols, int Kdim)
{
    __shared__ float As[16][68];
    __shared__ float Bs[16][68];
    const int tid = threadIdx.x;
    const int tx = tid & 15;   // col group (4 cols)
    const int ty = tid >> 4;   // row group (4 rows)
    const int rowBase = blockIdx.x * 64;
    const int colBase = blockIdx.y * 64;

    const int l_r = tid >> 2;         // 0..63 tile row
    const int l_k = (tid & 3) << 2;   // 0,4,8,12

    const int growA = rowBase + l_r;
    const bool aok = growA < Mrows;
    long abase = 0;
    if (aok) {
        const int ar = HAS_IDX ? rowidx[growA] : growA;
        abase = (long)ar * lda;
    }
    const long bbase = (long)(colBase + l_r) * ldb + boff;

    float acc[4][4] = {};

    for (int k0 = 0; k0 < Kdim; k0 += 16) {
        const int kk = k0 + l_k;
        float4 av = make_float4(0.f, 0.f, 0.f, 0.f);
        if (aok) {
            const float* ap = A + abase + kk;
            if (kk + 3 < Kdim) {
                av = *reinterpret_cast<const float4*>(ap);
            } else {
                if (kk     < Kdim) av.x = ap[0];
                if (kk + 1 < Kdim) av.y = ap[1];
                if (kk + 2 < Kdim) av.z = ap[2];
                if (kk + 3 < Kdim) av.w = ap[3];
            }
        }
        As[l_k + 0][l_r] = av.x;
        As[l_k + 1][l_r] = av.y;
        As[l_k + 2][l_r] = av.z;
        As[l_k + 3][l_r] = av.w;

        float4 bv = make_float4(0.f, 0.f, 0.f, 0.f);
        {
            const float* bp = B + bbase + kk;
            if (kk + 3 < Kdim) {
                bv = *reinterpret_cast<const float4*>(bp);
            } else {
                if (kk     < Kdim) bv.x = bp[0];
                if (kk + 1 < Kdim) bv.y = bp[1];
                if (kk + 2 < Kdim) bv.z = bp[2];
                if (kk + 3 < Kdim) bv.w = bp[3];
            }
        }
        Bs[l_k + 0][l_r] = bv.x;
        Bs[l_k + 1][l_r] = bv.y;
        Bs[l_k + 2][l_r] = bv.z;
        Bs[l_k + 3][l_r] = bv.w;

        __syncthreads();

        #pragma unroll
        for (int k = 0; k < 16; k++) {
            const float4 ra = *reinterpret_cast<const float4*>(&As[k][ty << 2]);
            const float4 rb = *reinterpret_cast<const float4*>(&Bs[k][tx << 2]);
            const float a_[4] = {ra.x, ra.y, ra.z, ra.w};
            const float b_[4] = {rb.x, rb.y, rb.z, rb.w};
            #pragma unroll
            for (int i = 0; i < 4; i++)
                #pragma unroll
                for (int j = 0; j < 4; j++)
                    acc[i][j] = fmaf(a_[i], b_[j], acc[i][j]);
        }
        __syncthreads();
    }

    const int c0 = colBase + (tx << 2);
    float4 badd = make_float4(0.f, 0.f, 0.f, 0.f);
    if (bias) badd = *reinterpret_cast<const float4*>(&bias[c0]);
    #pragma unroll
    for (int i = 0; i < 4; i++) {
        const int r = rowBase + (ty << 2) + i;
        if (r < Mrows) {
            float4 v;
            v.x = acc[i][0] + badd.x;
            v.y = acc[i][1] + badd.y;
            v.z = acc[i][2] + badd.z;
            v.w = acc[i][3] + badd.w;
            if (HAS_ADD) {
                const int lab = addidx[r];
                const float4 p =
                    *reinterpret_cast<const float4*>(&addvec[(long)lab * OUT2 + c0]);
                v.x += p.x; v.y += p.y; v.z += p.z; v.w += p.w;
            }
            *reinterpret_cast<float4*>(&C[(long)r * ldc + c0]) = v;
        }
    }
}

// ---------------------------------------------------------------------------
// fp16-MFMA GEMM with in-kernel fp32->fp16 conversion during LDS staging.
// C[r,c] = sum_k A[r,k]*B[c,k] + bias[c].  A [Mrows,lda] fp32, B [Ncols,ldb]
// fp32 weights. 128x128 tile, 4 waves (2x2 of 64x64), mfma_f32_16x16x32_f16.
// K-loop padded to 64; guarded tail iteration zero-fills k >= Kdim (no OOB).
// Grid: ((Mrows+127)/128, Ncols/128).
// ---------------------------------------------------------------------------
__global__ __launch_bounds__(256) void mfma_gemm_f16(
    const float* __restrict__ A, int lda,
    const float* __restrict__ B, int ldb,
    const float* __restrict__ bias,
    float* __restrict__ C, int ldc,
    int Mrows, int Kdim)
{
    __shared__ __align__(16) _Float16 As[128][72];
    __shared__ __align__(16) _Float16 Bs[128][72];

    const int tid  = threadIdx.x;
    const int wave = tid >> 6;
    const int lane = tid & 63;
    const int wr = (wave >> 1) * 64;   // wave row offset in tile
    const int wc = (wave & 1) * 64;    // wave col offset in tile
    const int lr = lane & 15;
    const int lk = (lane >> 4) << 3;   // 0,8,16,24

    const int mbase = blockIdx.x * 128;
    const int nbase = blockIdx.y * 128;

    // staging: 8 threads/row, 8 fp32 -> 8 f16 (16B LDS write) each
    const int s_row = tid >> 3;          // 0..31
    const int s_k   = (tid & 7) << 3;    // 0..56

    long abase[4];
    #pragma unroll
    for (int i = 0; i < 4; i++) {
        const int gm = mbase + s_row + 32 * i;
        abase[i] = (long)(gm < Mrows ? gm : 0) * lda;
    }
    long bbase[4];
    #pragma unroll
    for (int i = 0; i < 4; i++)
        bbase[i] = (long)(nbase + s_row + 32 * i) * ldb;

    f32x4 acc[4][4];
    #pragma unroll
    for (int f = 0; f < 4; f++)
        #pragma unroll
        for (int g = 0; g < 4; g++)
            acc[f][g] = f32x4{0.f, 0.f, 0.f, 0.f};

    const int Kpad = (Kdim + 63) & ~63;

    for (int k0 = 0; k0 < Kpad; k0 += 64) {
        if (k0 + 63 < Kdim) {
            // fast path: unguarded float4 pairs
            #pragma unroll
            for (int i = 0; i < 4; i++) {
                const float* ap = A + abase[i] + k0 + s_k;
                const float4 v0 = *reinterpret_cast<const float4*>(ap);
                const float4 v1 = *reinterpret_cast<const float4*>(ap + 4);
                f16x8 p;
                p[0] = (_Float16)v0.x; p[1] = (_Float16)v0.y;
                p[2] = (_Float16)v0.z; p[3] = (_Float16)v0.w;
                p[4] = (_Float16)v1.x; p[5] = (_Float16)v1.y;
                p[6] = (_Float16)v1.z; p[7] = (_Float16)v1.w;
                *reinterpret_cast<f16x8*>(&As[s_row + 32 * i][s_k]) = p;
            }
            #pragma unroll
            for (int i = 0; i < 4; i++) {
                const float* bp = B + bbase[i] + k0 + s_k;
                const float4 v0 = *reinterpret_cast<const float4*>(bp);
                const float4 v1 = *reinterpret_cast<const float4*>(bp + 4);
                f16x8 p;
                p[0] = (_Float16)v0.x; p[1] = (_Float16)v0.y;
                p[2] = (_Float16)v0.z; p[3] = (_Float16)v0.w;
                p[4] = (_Float16)v1.x; p[5] = (_Float16)v1.y;
                p[6] = (_Float16)v1.z; p[7] = (_Float16)v1.w;
                *reinterpret_cast<f16x8*>(&Bs[s_row + 32 * i][s_k]) = p;
            }
        } else {
            // tail: per-element guard, zero-fill k >= Kdim
            #pragma unroll
            for (int i = 0; i < 4; i++) {
                f16x8 p;
                #pragma unroll
                for (int j = 0; j < 8; j++) {
                    const int k = k0 + s_k + j;
                    p[j] = (_Float16)(k < Kdim ? A[abase[i] + k] : 0.f);
                }
                *reinterpret_cast<f16x8*>(&As[s_row + 32 * i][s_k]) = p;
            }
            #pragma unroll
            for (int i = 0; i < 4; i++) {
                f16x8 p;
                #pragma unroll
                for (int j = 0; j < 8; j++) {
                    const int k = k0 + s_k + j;
                    p[j] = (_Float16)(k < Kdim ? B[bbase[i] + k] : 0.f);
                }
                *reinterpret_cast<f16x8*>(&Bs[s_row + 32 * i][s_k]) = p;
            }
        }
        __syncthreads();

        #pragma unroll
        for (int kk = 0; kk < 64; kk += 32) {
            f16x8 af[4], bfr[4];
            #pragma unroll
            for (int f = 0; f < 4; f++)
                af[f] = *reinterpret_cast<const f16x8*>(&As[wr + f * 16 + lr][kk + lk]);
            #pragma unroll
            for (int g = 0; g < 4; g++)
                bfr[g] = *reinterpret_cast<const f16x8*>(&Bs[wc + g * 16 + lr][kk + lk]);
            #pragma unroll
            for (int f = 0; f < 4; f++)
                #pragma unroll
                for (int g = 0; g < 4; g++)
                    acc[f][g] = __builtin_amdgcn_mfma_f32_16x16x32_f16(
                        af[f], bfr[g], acc[f][g], 0, 0, 0);
        }
        __syncthreads();
    }

    const int rbase = (lane >> 4) << 2;
    #pragma unroll
    for (int f = 0; f < 4; f++) {
        #pragma unroll
        for (int r = 0; r < 4; r++) {
            const int m = mbase + wr + f * 16 + rbase + r;
            if (m < Mrows) {
                float* crow = C + (long)m * ldc;
                #pragma unroll
                for (int g = 0; g < 4; g++) {
                    const int c = nbase + wc + g * 16 + lr;
                    crow[c] = acc[f][g][r] + bias[c];
                }
            }
        }
    }
}

// ---------------------------------------------------------------------------
// Fused bf16-MFMA final GEMM (unchanged from passing round-2 version).
// ---------------------------------------------------------------------------
__global__ __launch_bounds__(256) void final_gemm_bf16(
    const unsigned short* __restrict__ Ab,   // h2 bf16 [N_TOT][H_F]
    const unsigned short* __restrict__ Wb,   // Wfc bf16 [OUT2][2*H_F]
    const float* __restrict__ bias,          // bfc [OUT2]
    const float* __restrict__ P,             // [K_CL][OUT2]  (cf @ WfcB.T)
    const float* __restrict__ Q,             // [K_CL][OUT2]  (cf @ WfcA.T)
    const int* __restrict__ labels,
    const int* __restrict__ rowidx,
    float* __restrict__ out)                 // [2*M_ROWS][OUT2]
{
    __shared__ __align__(16) unsigned short As[128][72];
    __shared__ __align__(16) unsigned short Bs[128][72];

    const int tid  = threadIdx.x;
    const int wave = tid >> 6;
    const int lane = tid & 63;
    const int wr = (wave >> 1) * 64;
    const int wc = (wave & 1) * 64;
    const int lr = lane & 15;
    const int lk = (lane >> 4) << 3;

    const int mbase = blockIdx.x * 128;
    const int half  = blockIdx.y >> 3;
    const int nbase = (blockIdx.y & 7) * 128;
    const int boff  = half ? H_F : 0;

    const int s_row = tid >> 3;
    const int s_k   = (tid & 7) << 3;

    long arow[4];
    #pragma unroll
    for (int i = 0; i < 4; i++) {
        const int gm = mbase + s_row + 32 * i;
        const int r = (gm < M_ROWS) ? rowidx[gm] : 0;
        arow[i] = (long)r * H_F + s_k;
    }
    long brow[4];
    #pragma unroll
    for (int i = 0; i < 4; i++)
        brow[i] = (long)(nbase + s_row + 32 * i) * (2 * H_F) + boff + s_k;

    f32x4 acc[4][4];
    #pragma unroll
    for (int f = 0; f < 4; f++)
        #pragma unroll
        for (int g = 0; g < 4; g++)
            acc[f][g] = f32x4{0.f, 0.f, 0.f, 0.f};

    for (int k0 = 0; k0 < H_F; k0 += 64) {
        #pragma unroll
        for (int i = 0; i < 4; i++) {
            const uint4 va = *reinterpret_cast<const uint4*>(Ab + arow[i] + k0);
            *reinterpret_cast<uint4*>(&As[s_row + 32 * i][s_k]) = va;
        }
        #pragma unroll
        for (int i = 0; i < 4; i++) {
            const uint4 vb = *reinterpret_cast<const uint4*>(Wb + brow[i] + k0);
            *reinterpret_cast<uint4*>(&Bs[s_row + 32 * i][s_k]) = vb;
        }
        __syncthreads();

        #pragma unroll
        for (int kk = 0; kk < 64; kk += 32) {
            bf16x8 af[4], bfr[4];
            #pragma unroll
            for (int f = 0; f < 4; f++)
                af[f] = *reinterpret_cast<const bf16x8*>(&As[wr + f * 16 + lr][kk + lk]);
            #pragma unroll
            for (int g = 0; g < 4; g++)
                bfr[g] = *reinterpret_cast<const bf16x8*>(&Bs[wc + g * 16 + lr][kk + lk]);
            #pragma unroll
            for (int f = 0; f < 4; f++)
                #pragma unroll
                for (int g = 0; g < 4; g++)
                    acc[f][g] = __builtin_amdgcn_mfma_f32_16x16x32_bf16(
                        af[f], bfr[g], acc[f][g], 0, 0, 0);
        }
        __syncthreads();
    }

    const float* __restrict__ addv = half ? Q : P;
    float* __restrict__ outp = out + (half ? (long)M_ROWS * OUT2 : 0);
    const int rbase = (lane >> 4) << 2;
    #pragma unroll
    for (int f = 0; f < 4; f++) {
        #pragma unroll
        for (int r = 0; r < 4; r++) {
            const int m = mbase + wr + f * 16 + rbase + r;
            if (m < M_ROWS) {
                const long lab = labels[m];
                const float* pv = addv + lab * OUT2;
                float* orow = outp + (long)m * OUT2;
                #pragma unroll
                for (int g = 0; g < 4; g++) {
                    const int c = nbase + wc + g * 16 + lr;
                    orow[c] = acc[f][g][r] + bias[c] + pv[c];
                }
            }
        }
    }
}

// Column sums + sumsq over h[rows, 256]. sums[0..255]=sum, sums[256..511]=sumsq.
__global__ __launch_bounds__(256) void bn_stats(
    const float* __restrict__ h, int rows, float* __restrict__ sums)
{
    const int col = threadIdx.x;
    const int per = (rows + gridDim.x - 1) / gridDim.x;
    const int r0 = blockIdx.x * per;
    const int r1 = min(rows, r0 + per);
    float s = 0.f, ss = 0.f;
    for (int r = r0; r < r1; r++) {
        const float v = h[(long)r * H_F + col];
        s += v;
        ss = fmaf(v, v, ss);
    }
    atomicAdd(&sums[col], s);
    atomicAdd(&sums[col + H_F], ss);
}

__global__ __launch_bounds__(256) void bn_finalize(
    const float* __restrict__ sums, const float* __restrict__ g,
    const float* __restrict__ beta, float* __restrict__ ss_out)
{
    const int j = threadIdx.x;
    const float invN = 1.0f / (float)N_TOT;
    const float mean = sums[j] * invN;
    const float var  = sums[j + H_F] * invN - mean * mean;
    const float rs = rsqrtf(var + BN_EPS);
    const float sc = rs * g[j];
    ss_out[j] = sc;
    ss_out[j + H_F] = beta[j] - mean * sc;
}

// In-place y = relu(x*scale[col] + shift[col]); optionally also write bf16 copy.
__global__ __launch_bounds__(256) void bn_relu(
    float* __restrict__ h, const float* __restrict__ ss, int total4,
    unsigned short* __restrict__ hb)
{
    const int i = blockIdx.x * blockDim.x + threadIdx.x;
    if (i < total4) {
        float4 v = reinterpret_cast<float4*>(h)[i];
        const int c = (i << 2) & (H_F - 1);
        v.x = fmaxf(0.f, fmaf(v.x, ss[c + 0], ss[c + 256]));
        v.y = fmaxf(0.f, fmaf(v.y, ss[c + 1], ss[c + 257]));
        v.z = fmaxf(0.f, fmaf(v.z, ss[c + 2], ss[c + 258]));
        v.w = fmaxf(0.f, fmaf(v.w, ss[c + 3], ss[c + 259]));
        reinterpret_cast<float4*>(h)[i] = v;
        if (hb) {
            ushort4 b;
            b.x = f2bf(v.x); b.y = f2bf(v.y); b.z = f2bf(v.z); b.w = f2bf(v.w);
            reinterpret_cast<ushort4*>(hb)[i] = b;
        }
    }
}

// fp32 -> bf16 bulk cast (float4 -> ushort4 per thread)
__global__ __launch_bounds__(256) void cast_to_bf16(
    const float* __restrict__ src, unsigned short* __restrict__ dst, int n4)
{
    const int i = blockIdx.x * blockDim.x + threadIdx.x;
    if (i < n4) {
        const float4 v = reinterpret_cast<const float4*>(src)[i];
        ushort4 b;
        b.x = f2bf(v.x); b.y = f2bf(v.y); b.z = f2bf(v.z); b.w = f2bf(v.w);
        reinterpret_cast<ushort4*>(dst)[i] = b;
    }
}

// labels[m] = argmax(cluster_id[m,:])
__global__ __launch_bounds__(256) void labels_kernel(
    const float* __restrict__ cid, int* __restrict__ labels, int* __restrict__ counts)
{
    const int m = blockIdx.x * blockDim.x + threadIdx.x;
    if (m < M_ROWS) {
        const float* row = cid + (long)m * K_CL;
        int best = 0;
        float bv = row[0];
        for (int k = 1; k < K_CL; k++) {
            const float v = row[k];
            if (v > bv) { bv = v; best = k; }
        }
        labels[m] = best;
        atomicAdd(&counts[best], 1);
    }
}

// Per-block LDS [K,H] accumulator; thread j owns column j.
__global__ __launch_bounds__(256) void seg_sum(
    const float* __restrict__ h2, const int* __restrict__ cidx,
    const int* __restrict__ labels, float* __restrict__ csum)
{
    __shared__ float ls[K_CL * H_F];
    for (int i = threadIdx.x; i < K_CL * H_F; i += blockDim.x) ls[i] = 0.f;
    __syncthreads();
    const int per = (M_ROWS + gridDim.x - 1) / gridDim.x;
    const int m0 = blockIdx.x * per;
    const int m1 = min(M_ROWS, m0 + per);
    const int j = threadIdx.x;
    for (int m = m0; m < m1; m++) {
        const int lab = labels[m];
        const int row = cidx[m];
        ls[lab * H_F + j] += h2[(long)row * H_F + j];
    }
    __syncthreads();
    for (int i = threadIdx.x; i < K_CL * H_F; i += blockDim.x) {
        const float v = ls[i];
        if (v != 0.f) atomicAdd(&csum[i], v);
    }
}

__global__ __launch_bounds__(256) void cf_kernel(
    const float* __restrict__ csum, const int* __restrict__ counts,
    float* __restrict__ cf)
{
    const int i = blockIdx.x * blockDim.x + threadIdx.x;
    if (i < K_CL * H_F) {
        const int k = i >> 8;
        cf[i] = csum[i] / (float)counts[k];
    }
}

extern "C" void kernel_launch(void* const* d_in, const int* in_sizes, int n_in,
                              void* d_out, int out_size, void* d_ws, size_t ws_size,
                              hipStream_t stream)
{
    const float* x    = (const float*)d_in[0];
    const float* cid  = (const float*)d_in[1];
    const int*   cidx = (const int*)  d_in[2];
    const float* W1   = (const float*)d_in[3];
    const float* b1   = (const float*)d_in[4];
    const float* g1   = (const float*)d_in[5];
    const float* be1  = (const float*)d_in[6];
    const float* W2   = (const float*)d_in[7];
    const float* b2   = (const float*)d_in[8];
    const float* g2   = (const float*)d_in[9];
    const float* be2  = (const float*)d_in[10];
    const float* Wfc  = (const float*)d_in[11];
    const float* bfc  = (const float*)d_in[12];
    float* out = (float*)d_out;

    char* ws = (char*)d_ws;
    size_t off = 0;
    auto alloc = [&](size_t bytes) -> void* {
        void* p = ws + off;
        off += (bytes + 255) & ~(size_t)255;
        return p;
    };
    float* h1    = (float*)alloc((size_t)N_TOT * H_F * 4);
    float* h2    = (float*)alloc((size_t)N_TOT * H_F * 4);
    float* sums1 = (float*)alloc(2 * H_F * 4);
    float* ss1   = (float*)alloc(2 * H_F * 4);
    float* sums2 = (float*)alloc(2 * H_F * 4);
    float* ss2   = (float*)alloc(2 * H_F * 4);
    int*   counts= (int*)  alloc(K_CL * 4);
    int*   labels= (int*)  alloc(M_ROWS * 4);
    float* csum  = (float*)alloc(K_CL * H_F * 4);
    float* cf    = (float*)alloc(K_CL * H_F * 4);
    float* P     = (float*)alloc((size_t)K_CL * OUT2 * 4);
    float* Q     = (float*)alloc((size_t)K_CL * OUT2 * 4);
    (void)ws_size; (void)in_sizes; (void)n_in; (void)out_size;

    // bf16 buffers alias h1 (h1 is dead after the L2 GEMM reads it):
    //   h2b  = bf16(h2)  [N_TOT*H_F*2 = 51.2 MB]
    //   wfcb = bf16(Wfc) [OUT2*2*H_F*2 = 1 MB], placed right after h2b
    unsigned short* h2b  = (unsigned short*)h1;
    unsigned short* wfcb = h2b + (size_t)N_TOT * H_F;

    // Zero the accumulator span (sums1 .. csum inclusive; ws is poisoned 0xAA).
    {
        char* z0 = (char*)sums1;
        char* z1 = (char*)csum + ((K_CL * H_F * 4 + 255) & ~255);
        hipMemsetAsync(z0, 0, (size_t)(z1 - z0), stream);
    }

    const dim3 blk(256);

    // labels + counts (independent of the GEMM chain)
    labels_kernel<<<dim3((M_ROWS + 255) / 256), blk, 0, stream>>>(cid, labels, counts);

    // layer 1: h1 = relu(bn(x @ W1.T + b1))  [fp16 MFMA, in-kernel convert]
    mfma_gemm_f16<<<dim3((N_TOT + 127) / 128, H_F / 128), blk, 0, stream>>>(
        x, IN_F, W1, IN_F, b1, h1, H_F, N_TOT, IN_F);
    bn_stats<<<dim3(256), blk, 0, stream>>>(h1, N_TOT, sums1);
    bn_finalize<<<dim3(1), blk, 0, stream>>>(sums1, g1, be1, ss1);
    bn_relu<<<dim3((N_TOT * H_F / 4 + 255) / 256), blk, 0, stream>>>(
        h1, ss1, N_TOT * H_F / 4, nullptr);

    // layer 2: h2 = relu(bn(h1 @ W2.T + b2))  [fp16 MFMA] (last reader of h1)
    mfma_gemm_f16<<<dim3((N_TOT + 127) / 128, H_F / 128), blk, 0, stream>>>(
        h1, H_F, W2, H_F, b2, h2, H_F, N_TOT, H_F);

    // h1 is now dead: safe to overwrite its buffer with bf16 data.
    cast_to_bf16<<<dim3((OUT2 * 2 * H_F / 4 + 255) / 256), blk, 0, stream>>>(
        Wfc, wfcb, OUT2 * 2 * H_F / 4);

    bn_stats<<<dim3(256), blk, 0, stream>>>(h2, N_TOT, sums2);
    bn_finalize<<<dim3(1), blk, 0, stream>>>(sums2, g2, be2, ss2);
    bn_relu<<<dim3((N_TOT * H_F / 4 + 255) / 256), blk, 0, stream>>>(
        h2, ss2, N_TOT * H_F / 4, h2b);

    // cluster mean features cf[K,H] (fp32 path, unchanged)
    seg_sum<<<dim3(100), blk, 0, stream>>>(h2, cidx, labels, csum);
    cf_kernel<<<dim3((K_CL * H_F + 255) / 256), blk, 0, stream>>>(csum, counts, cf);

    // P = cf @ WfcB.T ; Q = cf @ WfcA.T   (tiny, fp32, unchanged)
    gemm_kernel<false, false><<<dim3(1, OUT2 / 64), blk, 0, stream>>>(
        cf, H_F, Wfc, 2 * H_F, H_F, nullptr, nullptr, nullptr, nullptr, P, OUT2, K_CL, OUT2, H_F);
    gemm_kernel<false, false><<<dim3(1, OUT2 / 64), blk, 0, stream>>>(
        cf, H_F, Wfc, 2 * H_F, 0, nullptr, nullptr, nullptr, nullptr, Q, OUT2, K_CL, OUT2, H_F);

    // Fused bf16-MFMA final GEMM:
    //   y<8 :  out[m]     = xc@WfcA.T + P[label[m]] + bfc
    //   y>=8:  out[M+m]   = xc@WfcB.T + Q[label[m]] + bfc
    final_gemm_bf16<<<dim3((M_ROWS + 127) / 128, 16), blk, 0, stream>>>(
        h2b, wfcb, bfc, P, Q, labels, cidx, out);
}